// Round 1
// baseline (286.099 us; speedup 1.0000x reference)
//
#include <hip/hip_runtime.h>
#include <math.h>

// Problem: x (B=2, C=64, T=16, H=128, W=128) fp32; w (1,2,7,7,7) fp32.
// out = sigmoid(conv3d(concat[max_c(x), mean_c(x)], w, pad=3)) * x
//
// R4 structure: 3 kernels (decouple conv from streaming multiply).
//   K1 pool:  x (128 MiB) -> pmax|pavg (4 MiB)            [HBM-bound, ~22 us]
//   K2 conv:  7x7x7 conv over pooled -> attn (2 MiB, ws)  [LDS/VALU, ~20 us]
//             - LDS row stride 40 (16B-aligned) -> b128/b64 reads (140->42 instr)
//             - fixed-trip unroll-12 staging (12 L2 loads in flight vs serial)
//   K3 mul:   out = attn * x, 2048 blocks (32 waves/CU)   [HBM-bound, ~45 us]
//             - attn hoisted (2 loads/thread since B=2), nt stores
// Fallback: if ws < 6 MiB, use the previous verified fused conv+mul kernel.

#define NP (2 * 16 * 128 * 128) // 524288 pooled points per channel

typedef float vfloat4 __attribute__((ext_vector_type(4)));
typedef float vfloat2 __attribute__((ext_vector_type(2)));

// ---------------- Kernel 1: channel max + mean pool (float4) ----------------
__global__ __launch_bounds__(256) void pool_kernel(const float* __restrict__ x,
                                                   float* __restrict__ pmax,
                                                   float* __restrict__ pavg) {
    int j = blockIdx.x * 256 + threadIdx.x; // float4 index in pooled space, [0, 131072)
    int b = j >> 16;                        // 65536 float4 per batch in pooled space
    int rest = j & 65535;
    const float4* x4 = (const float4*)x;
    int base = (b << 22) | rest;            // float4 index into x for c=0

    float4 v = x4[base];
    float4 vmax = v;
    float4 vsum = v;
#pragma unroll 8
    for (int c = 1; c < 64; ++c) {
        float4 u = x4[base + (c << 16)];
        vmax.x = fmaxf(vmax.x, u.x);
        vmax.y = fmaxf(vmax.y, u.y);
        vmax.z = fmaxf(vmax.z, u.z);
        vmax.w = fmaxf(vmax.w, u.w);
        vsum.x += u.x; vsum.y += u.y; vsum.z += u.z; vsum.w += u.w;
    }
    const float s = 1.0f / 64.0f;
    float4 vavg; vavg.x = vsum.x * s; vavg.y = vsum.y * s; vavg.z = vsum.z * s; vavg.w = vsum.w * s;
    ((float4*)pmax)[j] = vmax;
    ((float4*)pavg)[j] = vavg;
}

// -------- Kernel 2: 7x7x7 conv (2ch) + sigmoid -> attn (float4 stores) ------
// Block = 256 threads handles one (b, t) and a 32x32 (h,w) tile.
// LDS stages one dz-plane of the 2-channel pooled halo: 2 x 38 x 40 (stride 40
// keeps each thread's 10-wide row 16B-aligned -> ds_read_b128/b64).
__global__ __launch_bounds__(256) void conv_kernel(const float* __restrict__ pooled, // pmax | pavg contiguous
                                                   const float* __restrict__ wgt,    // (1,2,7,7,7)
                                                   float* __restrict__ attn) {
    __shared__ __align__(16) float sm[2 * 38 * 40]; // 12160 B

    int bid = blockIdx.x;
    int tw0 = (bid & 3) << 5;
    int th0 = ((bid >> 2) & 3) << 5;
    int t = (bid >> 4) & 15;
    int b = bid >> 8;

    int tid = threadIdx.x;
    int ty = tid >> 3;         // 0..31 output row within tile
    int txg = (tid & 7) << 2;  // 0,4,...,28 output col group (4 consecutive w)

    float acc0 = 0.f, acc1 = 0.f, acc2 = 0.f, acc3 = 0.f;

    for (int dz = 0; dz < 7; ++dz) {
        int tsrc = t + dz - 3;
        if (tsrc < 0 || tsrc >= 16) continue; // block-uniform: barriers stay uniform

        __syncthreads(); // protect LDS from previous plane's readers
        // Fixed-trip staging: 12 predicated iterations so all 12 global loads
        // issue independently (the old variable-trip loop serialized on L2 latency).
#pragma unroll
        for (int r = 0; r < 12; ++r) {
            int i = tid + (r << 8);
            int ch = i / 1444;
            int rem = i - ch * 1444;
            int y = rem / 38;
            int xx = rem - y * 38;
            int gh = th0 + y - 3;
            int gw = tw0 + xx - 3;
            float val = 0.f;
            if (i < 2888 && (unsigned)gh < 128u && (unsigned)gw < 128u)
                val = pooled[ch * NP + (((b << 4) + tsrc) << 14) + (gh << 7) + gw];
            if (i < 2888)
                sm[ch * 1520 + y * 40 + xx] = val;
        }
        __syncthreads();

        const float* wdz = wgt + dz * 49;
#pragma unroll
        for (int ch = 0; ch < 2; ++ch) {
#pragma unroll
            for (int dy = 0; dy < 7; ++dy) {
                const float* rp = &sm[ch * 1520 + (ty + dy) * 40 + txg];
                vfloat4 r0 = *(const vfloat4*)rp;        // row[0..3]  (16B-aligned)
                vfloat4 r1 = *(const vfloat4*)(rp + 4);  // row[4..7]
                vfloat2 r2 = *(const vfloat2*)(rp + 8);  // row[8..9]
                float row[10] = {r0.x, r0.y, r0.z, r0.w,
                                 r1.x, r1.y, r1.z, r1.w,
                                 r2.x, r2.y};
                const float* wr = wdz + ch * 343 + dy * 7;
#pragma unroll
                for (int dx = 0; dx < 7; ++dx) {
                    float wv = wr[dx];
                    acc0 = fmaf(wv, row[dx + 0], acc0);
                    acc1 = fmaf(wv, row[dx + 1], acc1);
                    acc2 = fmaf(wv, row[dx + 2], acc2);
                    acc3 = fmaf(wv, row[dx + 3], acc3);
                }
            }
        }
    }

    vfloat4 av;
    av.x = 1.f / (1.f + __expf(-acc0));
    av.y = 1.f / (1.f + __expf(-acc1));
    av.z = 1.f / (1.f + __expf(-acc2));
    av.w = 1.f / (1.f + __expf(-acc3));

    // attn float4 index = b<<16 | t<<12 | h<<5 | w/4
    int aidx = (((b << 4) + t) << 12) + ((th0 + ty) << 5) + ((tw0 + txg) >> 2);
    ((vfloat4*)attn)[aidx] = av;
}

// ------------- Kernel 3: out = attn * x (pure streaming, 32 waves/CU) -------
// 2048 blocks x 256 threads; each thread owns one spatial float4 (s) and one
// channel residue c0, streams 8 channels for each of the 2 batches. attn is
// loaded once per batch (L2-resident, 2 MiB).
__global__ __launch_bounds__(256) void mul_kernel(const float* __restrict__ x,
                                                  const float* __restrict__ attn,
                                                  float* __restrict__ out) {
    int g = blockIdx.x * 256 + threadIdx.x; // [0, 524288)
    int s = g & 65535;                      // spatial float4 index within (b,c)
    int c0 = g >> 16;                       // 0..7 channel residue
    const vfloat4* x4 = (const vfloat4*)x;
    const vfloat4* a4 = (const vfloat4*)attn;
    vfloat4* o4 = (vfloat4*)out;
#pragma unroll
    for (int b = 0; b < 2; ++b) {
        vfloat4 a = a4[(b << 16) | s];
        int base = (b << 22) | (c0 << 16) | s;
#pragma unroll
        for (int k = 0; k < 8; ++k) {
            int idx = base + (k << 19); // channel += 8 per step
            __builtin_nontemporal_store(x4[idx] * a, &o4[idx]);
        }
    }
}

// ---------- Fallback: previous verified fused conv+sigmoid+mul kernel -------
__global__ __launch_bounds__(256) void conv_mul_fused(const float* __restrict__ pooled,
                                                      const float* __restrict__ wgt,
                                                      const float* __restrict__ x,
                                                      float* __restrict__ out) {
    __shared__ float sm[2 * 38 * 39]; // 11856 B

    int bid = blockIdx.x;
    int tw0 = (bid & 3) << 5;
    int th0 = ((bid >> 2) & 3) << 5;
    int t = (bid >> 4) & 15;
    int b = bid >> 8;

    int tid = threadIdx.x;
    int ty = tid >> 3;
    int txg = (tid & 7) << 2;

    int base4 = (b << 22) + (t << 12) + ((th0 + ty) << 5) + ((tw0 + txg) >> 2);
    int cs = bid & 63;
    const vfloat4* x4 = (const vfloat4*)x;
    vfloat4* o4 = (vfloat4*)out;

    vfloat4 pre[8];
#pragma unroll
    for (int k = 0; k < 8; ++k)
        pre[k] = x4[base4 + (((cs + k) & 63) << 16)];

    float acc0 = 0.f, acc1 = 0.f, acc2 = 0.f, acc3 = 0.f;

    for (int dz = 0; dz < 7; ++dz) {
        int tsrc = t + dz - 3;
        if (tsrc < 0 || tsrc >= 16) continue;

        __syncthreads();
        for (int i = tid; i < 2 * 38 * 38; i += 256) {
            int ch = i / 1444;
            int rem = i - ch * 1444;
            int y = rem / 38;
            int xx = rem - y * 38;
            int gh = th0 + y - 3;
            int gw = tw0 + xx - 3;
            float val = 0.f;
            if ((unsigned)gh < 128u && (unsigned)gw < 128u)
                val = pooled[ch * NP + (((b << 4) + tsrc) << 14) + (gh << 7) + gw];
            sm[ch * (38 * 39) + y * 39 + xx] = val;
        }
        __syncthreads();

        const float* wdz = wgt + dz * 49;
#pragma unroll
        for (int ch = 0; ch < 2; ++ch) {
#pragma unroll
            for (int dy = 0; dy < 7; ++dy) {
                const float* rp = &sm[ch * (38 * 39) + (ty + dy) * 39 + txg];
                float row[10];
#pragma unroll
                for (int k = 0; k < 10; ++k) row[k] = rp[k];
                const float* wr = wdz + ch * 343 + dy * 7;
#pragma unroll
                for (int dx = 0; dx < 7; ++dx) {
                    float wv = wr[dx];
                    acc0 = fmaf(wv, row[dx + 0], acc0);
                    acc1 = fmaf(wv, row[dx + 1], acc1);
                    acc2 = fmaf(wv, row[dx + 2], acc2);
                    acc3 = fmaf(wv, row[dx + 3], acc3);
                }
            }
        }
    }

    vfloat4 av;
    av.x = 1.f / (1.f + __expf(-acc0));
    av.y = 1.f / (1.f + __expf(-acc1));
    av.z = 1.f / (1.f + __expf(-acc2));
    av.w = 1.f / (1.f + __expf(-acc3));

#pragma unroll
    for (int k = 0; k < 8; ++k) {
        int idx = base4 + (((cs + k) & 63) << 16);
        __builtin_nontemporal_store(pre[k] * av, &o4[idx]);
    }
#pragma unroll 8
    for (int k = 8; k < 64; ++k) {
        int idx = base4 + (((cs + k) & 63) << 16);
        vfloat4 xv = x4[idx];
        __builtin_nontemporal_store(xv * av, &o4[idx]);
    }
}

extern "C" void kernel_launch(void* const* d_in, const int* in_sizes, int n_in,
                              void* d_out, int out_size, void* d_ws, size_t ws_size,
                              hipStream_t stream) {
    const float* x = (const float*)d_in[0];
    const float* w = (const float*)d_in[1];
    float* out = (float*)d_out;
    float* ws = (float*)d_ws;

    float* pmax = ws;       // NP floats
    float* pavg = ws + NP;  // NP floats (must follow pmax: conv indexes ch*NP)

    pool_kernel<<<NP / 4 / 256, 256, 0, stream>>>(x, pmax, pavg);

    if (ws_size >= (size_t)(3 * NP) * sizeof(float)) {
        float* attn = ws + 2 * NP; // NP floats
        conv_kernel<<<2 * 16 * 4 * 4, 256, 0, stream>>>(pmax, w, attn);
        mul_kernel<<<2048, 256, 0, stream>>>(x, attn, out);
    } else {
        // Workspace too small for the split path: previous verified fused kernel.
        conv_mul_fused<<<2 * 16 * 4 * 4, 256, 0, stream>>>(pmax, w, x, out);
    }
}

// Round 3
// 266.665 us; speedup vs baseline: 1.0729x; 1.0729x over previous
//
#include <hip/hip_runtime.h>
#include <math.h>

// Problem: x (B=2, C=64, T=16, H=128, W=128) fp32; w (1,2,7,7,7) fp32.
// out = sigmoid(conv3d(concat[max_c(x), mean_c(x)], w, pad=3)) * x
//
// R5 structure (resubmitted R6 — prior round's bench timed out, never ran):
// 2 kernels (the 3-way split regressed: extra drain + lost conv<->stream
// overlap). Fused kernel gets the staging fixes developed in R4:
//   - fixed-trip unroll-12 predicated staging (12 independent L2 loads in
//     flight vs ~11 serial latency hops in the old variable-trip loop)
//   - LDS row stride 40 (16B-aligned): row reads b128+b128+b64 instead of
//     10x ds_read_b32 (140 -> 42 LDS instrs/thread/plane); stride 40 == 8
//     mod 32 banks keeps consecutive rows conflict-spread
//   - x prefetch deepened 8 -> 16 channels (~64 VGPRs parked through conv)
//   K1 pool:      x (128 MiB) -> pmax|pavg (4 MiB)      [HBM-bound, ~22 us]
//   K2 conv+mul:  conv3d (LDS per-plane) + sigmoid in regs, then stream all
//                 64 channels out = attn * x with non-temporal stores.

#define NP (2 * 16 * 128 * 128) // 524288 pooled points per channel

typedef float vfloat4 __attribute__((ext_vector_type(4)));
typedef float vfloat2 __attribute__((ext_vector_type(2)));

// ---------------- Kernel 1: channel max + mean pool (float4) ----------------
__global__ __launch_bounds__(256) void pool_kernel(const float* __restrict__ x,
                                                   float* __restrict__ pmax,
                                                   float* __restrict__ pavg) {
    int j = blockIdx.x * 256 + threadIdx.x; // float4 index in pooled space, [0, 131072)
    int b = j >> 16;                        // 65536 float4 per batch in pooled space
    int rest = j & 65535;
    const float4* x4 = (const float4*)x;
    int base = (b << 22) | rest;            // float4 index into x for c=0

    float4 v = x4[base];
    float4 vmax = v;
    float4 vsum = v;
#pragma unroll 8
    for (int c = 1; c < 64; ++c) {
        float4 u = x4[base + (c << 16)];
        vmax.x = fmaxf(vmax.x, u.x);
        vmax.y = fmaxf(vmax.y, u.y);
        vmax.z = fmaxf(vmax.z, u.z);
        vmax.w = fmaxf(vmax.w, u.w);
        vsum.x += u.x; vsum.y += u.y; vsum.z += u.z; vsum.w += u.w;
    }
    const float s = 1.0f / 64.0f;
    float4 vavg; vavg.x = vsum.x * s; vavg.y = vsum.y * s; vavg.z = vsum.z * s; vavg.w = vsum.w * s;
    ((float4*)pmax)[j] = vmax;
    ((float4*)pavg)[j] = vavg;
}

// -------- Kernel 2: 7x7x7 conv (2ch) + sigmoid + broadcast multiply ---------
// Block = 256 threads handles one (b, t) and a 32x32 (h,w) tile.
// LDS stages one dz-plane of the 2-channel pooled halo: 2 x 38 x 40 floats
// (stride 40 keeps each thread's 10-wide row 16B-aligned).
// Each thread computes attn for its own 4 consecutive-w pixels, keeps them in
// registers, then streams all 64 channels of x through them.
__global__ __launch_bounds__(256) void conv_mul_kernel(const float* __restrict__ pooled, // pmax | pavg contiguous
                                                       const float* __restrict__ wgt,    // (1,2,7,7,7)
                                                       const float* __restrict__ x,
                                                       float* __restrict__ out) {
    __shared__ __align__(16) float sm[2 * 38 * 40]; // 12160 B

    int bid = blockIdx.x;
    int tw0 = (bid & 3) << 5;
    int th0 = ((bid >> 2) & 3) << 5;
    int t = (bid >> 4) & 15;
    int b = bid >> 8;

    int tid = threadIdx.x;
    int ty = tid >> 3;         // 0..31 output row within tile
    int txg = (tid & 7) << 2;  // 0,4,...,28 output col group (4 consecutive w)

    // Phase-2 addressing, computed early so prefetch loads can issue now.
    // float4 index: b*2^22 + c*2^16 + t*2^12 + gh*2^5 + gw/4
    int base4 = (b << 22) + (t << 12) + ((th0 + ty) << 5) + ((tw0 + txg) >> 2);
    int cs = bid & 63; // per-block channel stagger
    const vfloat4* x4 = (const vfloat4*)x;
    vfloat4* o4 = (vfloat4*)out;

    // Prefetch first 16 staggered channels of x: loads fly during the conv
    // phase; data parks in VGPRs until the streaming phase.
    vfloat4 pre[16];
#pragma unroll
    for (int k = 0; k < 16; ++k)
        pre[k] = x4[base4 + (((cs + k) & 63) << 16)];

    float acc0 = 0.f, acc1 = 0.f, acc2 = 0.f, acc3 = 0.f;

    for (int dz = 0; dz < 7; ++dz) {
        int tsrc = t + dz - 3;
        if (tsrc < 0 || tsrc >= 16) continue; // block-uniform: barriers stay uniform

        __syncthreads(); // protect LDS from previous plane's readers
        // Fixed-trip staging: 12 predicated iterations so all 12 global loads
        // issue independently (a variable-trip loop serializes on L2 latency).
#pragma unroll
        for (int r = 0; r < 12; ++r) {
            int i = tid + (r << 8);
            int ch = i / 1444;
            int rem = i - ch * 1444;
            int y = rem / 38;
            int xx = rem - y * 38;
            int gh = th0 + y - 3;
            int gw = tw0 + xx - 3;
            float val = 0.f;
            if (i < 2888 && (unsigned)gh < 128u && (unsigned)gw < 128u)
                val = pooled[ch * NP + (((b << 4) + tsrc) << 14) + (gh << 7) + gw];
            if (i < 2888)
                sm[ch * 1520 + y * 40 + xx] = val;
        }
        __syncthreads();

        const float* wdz = wgt + dz * 49;
#pragma unroll
        for (int ch = 0; ch < 2; ++ch) {
#pragma unroll
            for (int dy = 0; dy < 7; ++dy) {
                const float* rp = &sm[ch * 1520 + (ty + dy) * 40 + txg];
                vfloat4 r0 = *(const vfloat4*)rp;        // row[0..3]  (16B-aligned)
                vfloat4 r1 = *(const vfloat4*)(rp + 4);  // row[4..7]
                vfloat2 r2 = *(const vfloat2*)(rp + 8);  // row[8..9]
                float row[10] = {r0.x, r0.y, r0.z, r0.w,
                                 r1.x, r1.y, r1.z, r1.w,
                                 r2.x, r2.y};
                const float* wr = wdz + ch * 343 + dy * 7;
#pragma unroll
                for (int dx = 0; dx < 7; ++dx) {
                    float wv = wr[dx];
                    acc0 = fmaf(wv, row[dx + 0], acc0);
                    acc1 = fmaf(wv, row[dx + 1], acc1);
                    acc2 = fmaf(wv, row[dx + 2], acc2);
                    acc3 = fmaf(wv, row[dx + 3], acc3);
                }
            }
        }
    }

    vfloat4 av;
    av.x = 1.f / (1.f + __expf(-acc0));
    av.y = 1.f / (1.f + __expf(-acc1));
    av.z = 1.f / (1.f + __expf(-acc2));
    av.w = 1.f / (1.f + __expf(-acc3));

    // Phase 2: out[b, c, t, gh, gw..gw+3] = attn * x, for all 64 channels,
    // staggered start channel per block; non-temporal stores keep x in L3.
#pragma unroll
    for (int k = 0; k < 16; ++k) {
        int idx = base4 + (((cs + k) & 63) << 16);
        __builtin_nontemporal_store(pre[k] * av, &o4[idx]);
    }
#pragma unroll 8
    for (int k = 16; k < 64; ++k) {
        int idx = base4 + (((cs + k) & 63) << 16);
        vfloat4 xv = x4[idx];
        __builtin_nontemporal_store(xv * av, &o4[idx]);
    }
}

extern "C" void kernel_launch(void* const* d_in, const int* in_sizes, int n_in,
                              void* d_out, int out_size, void* d_ws, size_t ws_size,
                              hipStream_t stream) {
    const float* x = (const float*)d_in[0];
    const float* w = (const float*)d_in[1];
    float* out = (float*)d_out;
    float* ws = (float*)d_ws;

    float* pmax = ws;       // NP floats
    float* pavg = ws + NP;  // NP floats (must follow pmax: conv indexes ch*NP)

    pool_kernel<<<NP / 4 / 256, 256, 0, stream>>>(x, pmax, pavg);
    conv_mul_kernel<<<2 * 16 * 4 * 4, 256, 0, stream>>>(pmax, w, x, out);
}